// Round 1
// baseline (1343.564 us; speedup 1.0000x reference)
//
#include <hip/hip_runtime.h>
#include <math.h>

#define Hh 128
#define Ww 128
#define HW (Hh*Ww)
#define Bn 4
#define Cn 64
#define On 64

// workspace layout (in floats)
#define OM_OFF   0                          // B*27*HW = 1,769,472 floats
#define CONV_OFF (Bn*27*HW)                 // B*64*HW = 4,194,304 floats
#define STAT_OFF (CONV_OFF + Bn*On*HW)      // 128 floats (sum[64], sumsq[64])
#define SS_OFF   (STAT_OFF + 128)           // 128 floats (scale[64], shift[64])

// ---------------------------------------------------------------------------
// Kernel A: offset-predicting 3x3 conv (C=64 -> 27), stride 1, pad 1.
// Channels 18..26 get sigmoid applied at store time (they are the mask).
// One thread per output pixel; 27 accumulators in registers.
// ---------------------------------------------------------------------------
__global__ __launch_bounds__(128) void offset_conv_k(
    const float* __restrict__ x, const float* __restrict__ ow,
    const float* __restrict__ ob, float* __restrict__ om)
{
    int bh = blockIdx.x;
    int b = bh >> 7;          // H = 128 rows per image
    int h = bh & 127;
    int w = threadIdx.x;

    float acc[27];
#pragma unroll
    for (int o = 0; o < 27; ++o) acc[o] = ob[o];

    const float* xb = x + (size_t)b * Cn * HW;
    for (int c = 0; c < Cn; ++c) {
        const float* xp = xb + c * HW;
        float v[9];
#pragma unroll
        for (int ky = 0; ky < 3; ++ky) {
            int yy = h + ky - 1;
            int yc = min(max(yy, 0), Hh - 1);
            bool vy = (yy >= 0) && (yy < Hh);
#pragma unroll
            for (int kx = 0; kx < 3; ++kx) {
                int xx = w + kx - 1;
                int xc = min(max(xx, 0), Ww - 1);
                bool vx = (xx >= 0) && (xx < Ww);
                float msk = (vy && vx) ? 1.0f : 0.0f;
                v[ky * 3 + kx] = xp[yc * Ww + xc] * msk;
            }
        }
        const float* wp = ow + c * 9;   // ow[o*576 + c*9 + t]
#pragma unroll
        for (int o = 0; o < 27; ++o) {
            const float* wo = wp + o * 576;
#pragma unroll
            for (int t = 0; t < 9; ++t) acc[o] += v[t] * wo[t];
        }
    }

    int p = h * Ww + w;
#pragma unroll
    for (int o = 0; o < 27; ++o) {
        float val = acc[o];
        if (o >= 18) val = 1.0f / (1.0f + __expf(-val));  // sigmoid for mask
        om[((size_t)b * 27 + o) * HW + p] = val;
    }
}

// ---------------------------------------------------------------------------
// Kernel B: deformable sampling + 3x3 DCN conv (C=64 -> O=64).
// One thread per pixel. Precompute per-tap clamped corner indices and
// validity*mask-folded bilinear weights, then loop channels:
//   s[k] = sum of 4 weighted corner loads;  acc[o] += s[k] * w[o][c][k].
// Writes conv_out and accumulates per-channel sum / sumsq via wave reduce.
// ---------------------------------------------------------------------------
__global__ __launch_bounds__(128) void dcn_k(
    const float* __restrict__ x, const float* __restrict__ om,
    const float* __restrict__ dw, float* __restrict__ conv,
    float* __restrict__ stats)
{
    int bh = blockIdx.x;
    int b = bh >> 7;
    int h = bh & 127;
    int w = threadIdx.x;
    int p = h * Ww + w;

    const float* omb = om + (size_t)b * 27 * HW;

    int   idx[9][4];
    float fw[9][4];
#pragma unroll
    for (int k = 0; k < 9; ++k) {
        float ox = omb[(size_t)(k) * HW + p];
        float oy = omb[(size_t)(9 + k) * HW + p];
        float m  = omb[(size_t)(18 + k) * HW + p];   // already sigmoided
        float py = (float)(h - 1 + k / 3) + oy;
        float px = (float)(w - 1 + k % 3) + ox;
        float y0f = floorf(py), x0f = floorf(px);
        int y0 = (int)y0f, x0 = (int)x0f;
        float wy = py - y0f, wx = px - x0f;
#pragma unroll
        for (int dy = 0; dy < 2; ++dy) {
#pragma unroll
            for (int dx = 0; dx < 2; ++dx) {
                int yi = y0 + dy, xi = x0 + dx;
                bool valid = (yi >= 0) && (yi <= Hh - 1) && (xi >= 0) && (xi <= Ww - 1);
                int yc = min(max(yi, 0), Hh - 1);
                int xc = min(max(xi, 0), Ww - 1);
                float wgt = (dy ? wy : 1.0f - wy) * (dx ? wx : 1.0f - wx);
                fw[k][dy * 2 + dx] = valid ? (wgt * m) : 0.0f;
                idx[k][dy * 2 + dx] = yc * Ww + xc;
            }
        }
    }

    float acc[On];
#pragma unroll
    for (int o = 0; o < On; ++o) acc[o] = 0.0f;

    const float* xb = x + (size_t)b * Cn * HW;
    for (int c = 0; c < Cn; ++c) {
        const float* xp = xb + c * HW;
        float s[9];
#pragma unroll
        for (int k = 0; k < 9; ++k) {
            s[k] = fw[k][0] * xp[idx[k][0]] + fw[k][1] * xp[idx[k][1]]
                 + fw[k][2] * xp[idx[k][2]] + fw[k][3] * xp[idx[k][3]];
        }
        const float* wp = dw + c * 9;   // dw[o*576 + c*9 + t]
#pragma unroll
        for (int o = 0; o < On; ++o) {
            const float* wo = wp + o * 576;
#pragma unroll
            for (int t = 0; t < 9; ++t) acc[o] += s[t] * wo[t];
        }
    }

    // store pre-BN conv output
    float* cv = conv + (size_t)b * On * HW;
#pragma unroll
    for (int o = 0; o < On; ++o) cv[(size_t)o * HW + p] = acc[o];

    // per-channel sum and sum-of-squares: wave reduce + one atomic per wave
#pragma unroll
    for (int o = 0; o < On; ++o) {
        float s1 = acc[o];
        float s2 = acc[o] * acc[o];
#pragma unroll
        for (int off = 32; off > 0; off >>= 1) {
            s1 += __shfl_down(s1, off, 64);
            s2 += __shfl_down(s2, off, 64);
        }
        if ((threadIdx.x & 63) == 0) {
            atomicAdd(&stats[o], s1);
            atomicAdd(&stats[64 + o], s2);
        }
    }
}

// ---------------------------------------------------------------------------
// Kernel C: finalize BN stats -> scale/shift per channel
// ---------------------------------------------------------------------------
__global__ void stats_k(const float* __restrict__ stats,
                        const float* __restrict__ gamma,
                        const float* __restrict__ beta,
                        float* __restrict__ ss)
{
    int o = threadIdx.x;
    if (o < On) {
        float n = (float)(Bn * HW);
        float mu = stats[o] / n;
        float var = stats[64 + o] / n - mu * mu;
        float sc = gamma[o] * rsqrtf(var + 1e-5f);
        ss[o] = sc;
        ss[64 + o] = beta[o] - mu * sc;
    }
}

// ---------------------------------------------------------------------------
// Kernel D: apply BN + ReLU, vectorized float4
// total elements = Bn*On*HW = 4,194,304  -> 1,048,576 float4
// ---------------------------------------------------------------------------
__global__ __launch_bounds__(256) void bnrelu_k(
    const float* __restrict__ conv, const float* __restrict__ ss,
    float* __restrict__ out)
{
    int i = blockIdx.x * blockDim.x + threadIdx.x;   // float4 index
    int ch = (i >> 12) & 63;                         // HW/4 = 4096 float4 per plane
    float sc = ss[ch];
    float sh = ss[64 + ch];
    const float4* cv = (const float4*)conv;
    float4* ov = (float4*)out;
    float4 v = cv[i];
    v.x = fmaxf(v.x * sc + sh, 0.0f);
    v.y = fmaxf(v.y * sc + sh, 0.0f);
    v.z = fmaxf(v.z * sc + sh, 0.0f);
    v.w = fmaxf(v.w * sc + sh, 0.0f);
    ov[i] = v;
}

// ---------------------------------------------------------------------------
extern "C" void kernel_launch(void* const* d_in, const int* in_sizes, int n_in,
                              void* d_out, int out_size, void* d_ws, size_t ws_size,
                              hipStream_t stream)
{
    const float* x     = (const float*)d_in[0];
    const float* ow    = (const float*)d_in[1];
    const float* ob    = (const float*)d_in[2];
    const float* dw    = (const float*)d_in[3];
    // d_in[4] = dcn_b: cancels exactly under BN mean subtraction -> unused
    const float* gamma = (const float*)d_in[5];
    const float* beta  = (const float*)d_in[6];

    float* ws    = (float*)d_ws;
    float* om    = ws + OM_OFF;
    float* conv  = ws + CONV_OFF;
    float* stats = ws + STAT_OFF;
    float* ss    = ws + SS_OFF;

    hipMemsetAsync(stats, 0, 128 * sizeof(float), stream);

    offset_conv_k<<<dim3(Bn * Hh), dim3(128), 0, stream>>>(x, ow, ob, om);
    dcn_k<<<dim3(Bn * Hh), dim3(128), 0, stream>>>(x, om, dw, conv, stats);
    stats_k<<<dim3(1), dim3(64), 0, stream>>>(stats, gamma, beta, ss);
    bnrelu_k<<<dim3(Bn * On * HW / 4 / 256), dim3(256), 0, stream>>>(conv, ss, (float*)d_out);
}

// Round 2
// 948.240 us; speedup vs baseline: 1.4169x; 1.4169x over previous
//
#include <hip/hip_runtime.h>
#include <math.h>

#define Hh 128
#define Ww 128
#define HW (Hh*Ww)
#define Bn 4
#define Cn 64
#define On 64

// workspace layout (in floats)
#define OM_OFF   0                          // B*27*HW = 1,769,472 floats
#define CONV_OFF (Bn*27*HW)                 // B*64*HW = 4,194,304 floats
#define STAT_OFF (CONV_OFF + Bn*On*HW)      // 128 floats (sum[64], sumsq[64])
#define SS_OFF   (STAT_OFF + 128)           // 128 floats (scale[64], shift[64])

// ---------------------------------------------------------------------------
// Kernel A: offset-predicting 3x3 conv (C=64 -> 27), stride 1, pad 1.
// Split into 3 output groups of 9 (grid.y) for occupancy; group 2 is the
// mask group -> sigmoid at store. One thread per pixel, 9 accumulators.
// ---------------------------------------------------------------------------
__global__ __launch_bounds__(128, 4) void offset_conv_k(
    const float* __restrict__ x, const float* __restrict__ ow,
    const float* __restrict__ ob, float* __restrict__ om)
{
    int bh = blockIdx.x;
    int g  = blockIdx.y;            // 0..2, output channels g*9 .. g*9+8
    int b = bh >> 7;
    int h = bh & 127;
    int w = threadIdx.x;
    int obase = g * 9;

    float acc[9];
#pragma unroll
    for (int o = 0; o < 9; ++o) acc[o] = ob[obase + o];

    const float* xb = x + (size_t)b * Cn * HW;
    for (int c = 0; c < Cn; ++c) {
        const float* xp = xb + c * HW;
        float v[9];
#pragma unroll
        for (int ky = 0; ky < 3; ++ky) {
            int yy = h + ky - 1;
            int yc = min(max(yy, 0), Hh - 1);
            bool vy = (yy >= 0) && (yy < Hh);
#pragma unroll
            for (int kx = 0; kx < 3; ++kx) {
                int xx = w + kx - 1;
                int xc = min(max(xx, 0), Ww - 1);
                bool vx = (xx >= 0) && (xx < Ww);
                v[ky * 3 + kx] = (vy && vx) ? xp[yc * Ww + xc] : 0.0f;
            }
        }
        const float* wp = ow + (size_t)obase * 576 + c * 9;
#pragma unroll
        for (int o = 0; o < 9; ++o) {
            const float* wo = wp + o * 576;
#pragma unroll
            for (int t = 0; t < 9; ++t) acc[o] += v[t] * wo[t];
        }
    }

    int p = h * Ww + w;
#pragma unroll
    for (int o = 0; o < 9; ++o) {
        float val = acc[o];
        if (g == 2) val = 1.0f / (1.0f + __expf(-val));  // sigmoid for mask
        om[((size_t)b * 27 + obase + o) * HW + p] = val;
    }
}

// ---------------------------------------------------------------------------
// Kernel B: deformable sampling + 3x3 DCN conv (C=64 -> O=64).
// Split into 4 output-channel groups of 16 (grid.y) -> 2048 blocks, 16
// waves/CU, and acc[16]+fw[36]+idx[36] fits in <128 VGPRs (no spills).
// ---------------------------------------------------------------------------
__global__ __launch_bounds__(128, 4) void dcn_k(
    const float* __restrict__ x, const float* __restrict__ om,
    const float* __restrict__ dw, float* __restrict__ conv,
    float* __restrict__ stats)
{
    int bh = blockIdx.x;
    int g  = blockIdx.y;            // 0..3, output channels g*16 .. g*16+15
    int b = bh >> 7;
    int h = bh & 127;
    int w = threadIdx.x;
    int p = h * Ww + w;
    int obase = g * 16;

    const float* omb = om + (size_t)b * 27 * HW;

    int   idx[9][4];
    float fw[9][4];
#pragma unroll
    for (int k = 0; k < 9; ++k) {
        float ox = omb[(size_t)(k) * HW + p];
        float oy = omb[(size_t)(9 + k) * HW + p];
        float m  = omb[(size_t)(18 + k) * HW + p];   // already sigmoided
        float py = (float)(h - 1 + k / 3) + oy;
        float px = (float)(w - 1 + k % 3) + ox;
        float y0f = floorf(py), x0f = floorf(px);
        int y0 = (int)y0f, x0 = (int)x0f;
        float wy = py - y0f, wx = px - x0f;
#pragma unroll
        for (int dy = 0; dy < 2; ++dy) {
#pragma unroll
            for (int dx = 0; dx < 2; ++dx) {
                int yi = y0 + dy, xi = x0 + dx;
                bool valid = (yi >= 0) && (yi <= Hh - 1) && (xi >= 0) && (xi <= Ww - 1);
                int yc = min(max(yi, 0), Hh - 1);
                int xc = min(max(xi, 0), Ww - 1);
                float wgt = (dy ? wy : 1.0f - wy) * (dx ? wx : 1.0f - wx);
                fw[k][dy * 2 + dx] = valid ? (wgt * m) : 0.0f;
                idx[k][dy * 2 + dx] = yc * Ww + xc;
            }
        }
    }

    float acc[16];
#pragma unroll
    for (int o = 0; o < 16; ++o) acc[o] = 0.0f;

    const float* xb = x + (size_t)b * Cn * HW;
    for (int c = 0; c < Cn; ++c) {
        const float* xp = xb + c * HW;
        float s[9];
#pragma unroll
        for (int k = 0; k < 9; ++k) {
            s[k] = fw[k][0] * xp[idx[k][0]] + fw[k][1] * xp[idx[k][1]]
                 + fw[k][2] * xp[idx[k][2]] + fw[k][3] * xp[idx[k][3]];
        }
        const float* wp = dw + (size_t)obase * 576 + c * 9;
#pragma unroll
        for (int o = 0; o < 16; ++o) {
            const float* wo = wp + o * 576;
#pragma unroll
            for (int t = 0; t < 9; ++t) acc[o] += s[t] * wo[t];
        }
    }

    // store pre-BN conv output
    float* cv = conv + ((size_t)b * On + obase) * HW;
#pragma unroll
    for (int o = 0; o < 16; ++o) cv[(size_t)o * HW + p] = acc[o];

    // per-channel sum and sum-of-squares: wave reduce + one atomic per wave
#pragma unroll
    for (int o = 0; o < 16; ++o) {
        float s1 = acc[o];
        float s2 = acc[o] * acc[o];
#pragma unroll
        for (int off = 32; off > 0; off >>= 1) {
            s1 += __shfl_down(s1, off, 64);
            s2 += __shfl_down(s2, off, 64);
        }
        if ((threadIdx.x & 63) == 0) {
            atomicAdd(&stats[obase + o], s1);
            atomicAdd(&stats[64 + obase + o], s2);
        }
    }
}

// ---------------------------------------------------------------------------
// Kernel C: finalize BN stats -> scale/shift per channel
// ---------------------------------------------------------------------------
__global__ void stats_k(const float* __restrict__ stats,
                        const float* __restrict__ gamma,
                        const float* __restrict__ beta,
                        float* __restrict__ ss)
{
    int o = threadIdx.x;
    if (o < On) {
        float n = (float)(Bn * HW);
        float mu = stats[o] / n;
        float var = stats[64 + o] / n - mu * mu;
        float sc = gamma[o] * rsqrtf(var + 1e-5f);
        ss[o] = sc;
        ss[64 + o] = beta[o] - mu * sc;
    }
}

// ---------------------------------------------------------------------------
// Kernel D: apply BN + ReLU, vectorized float4
// ---------------------------------------------------------------------------
__global__ __launch_bounds__(256) void bnrelu_k(
    const float* __restrict__ conv, const float* __restrict__ ss,
    float* __restrict__ out)
{
    int i = blockIdx.x * blockDim.x + threadIdx.x;   // float4 index
    int ch = (i >> 12) & 63;                         // HW/4 = 4096 float4 per plane
    float sc = ss[ch];
    float sh = ss[64 + ch];
    const float4* cv = (const float4*)conv;
    float4* ov = (float4*)out;
    float4 v = cv[i];
    v.x = fmaxf(v.x * sc + sh, 0.0f);
    v.y = fmaxf(v.y * sc + sh, 0.0f);
    v.z = fmaxf(v.z * sc + sh, 0.0f);
    v.w = fmaxf(v.w * sc + sh, 0.0f);
    ov[i] = v;
}

// ---------------------------------------------------------------------------
extern "C" void kernel_launch(void* const* d_in, const int* in_sizes, int n_in,
                              void* d_out, int out_size, void* d_ws, size_t ws_size,
                              hipStream_t stream)
{
    const float* x     = (const float*)d_in[0];
    const float* ow    = (const float*)d_in[1];
    const float* ob    = (const float*)d_in[2];
    const float* dw    = (const float*)d_in[3];
    // d_in[4] = dcn_b: cancels exactly under BN mean subtraction -> unused
    const float* gamma = (const float*)d_in[5];
    const float* beta  = (const float*)d_in[6];

    float* ws    = (float*)d_ws;
    float* om    = ws + OM_OFF;
    float* conv  = ws + CONV_OFF;
    float* stats = ws + STAT_OFF;
    float* ss    = ws + SS_OFF;

    hipMemsetAsync(stats, 0, 128 * sizeof(float), stream);

    offset_conv_k<<<dim3(Bn * Hh, 3), dim3(128), 0, stream>>>(x, ow, ob, om);
    dcn_k<<<dim3(Bn * Hh, 4), dim3(128), 0, stream>>>(x, om, dw, conv, stats);
    stats_k<<<dim3(1), dim3(64), 0, stream>>>(stats, gamma, beta, ss);
    bnrelu_k<<<dim3(Bn * On * HW / 4 / 256), dim3(256), 0, stream>>>(conv, ss, (float*)d_out);
}